// Round 14
// baseline (124.548 us; speedup 1.0000x reference)
//
#include <hip/hip_runtime.h>

#define NN 100000
#define NE 1600000
#define D 64

#define BKT 256                          // buckets (both row- and col-space)
#define BROWS ((NN + BKT - 1) / BKT)     // 391 per bucket (fits 9 bits)
#define CAP 8192                         // buck slots per bucket (mean 6250, sigma 79)
#define PADCAP 12288                     // adjc slots per bucket (rows padded to x16)
#define P1_NB 1024                       // pass-1 blocks (4 per CU)
#define P1_T 512                         // pass-1 threads per block
#define EPB ((NE + P1_NB - 1) / P1_NB)   // 1563 edges per pass-1 block

typedef unsigned short u16;
typedef unsigned int u32;
typedef unsigned char u8;
typedef __attribute__((ext_vector_type(8))) unsigned short us8;

// ---------------- bf16 helpers (bit-level, RNE) ----------------

__device__ __forceinline__ float bf2f(u16 u) {
    union { u32 i; float f; } x; x.i = ((u32)u) << 16; return x.f;
}
__device__ __forceinline__ u16 f2bf(float f) {
    union { float f; u32 i; } x; x.f = f;
    u32 r = x.i + 0x7FFF + ((x.i >> 16) & 1);   // round-to-nearest-even
    return (u16)(r >> 16);
}

// Setup: zero bucket counters + softmax of the 3 hop weights.
__global__ void setup_kernel(const float* __restrict__ hw, float* __restrict__ wsm,
                             int* __restrict__ bcnt, int* __restrict__ bcnt2) {
    int t = threadIdx.x;
    if (t < BKT) bcnt[t] = 0;
    else if (t < 2 * BKT) bcnt2[t - BKT] = 0;
    else if (t == 2 * BKT) {
        float m = fmaxf(fmaxf(hw[0], hw[1]), hw[2]);
        float e0 = expf(hw[0] - m), e1 = expf(hw[1] - m), e2 = expf(hw[2] - m);
        float s = e0 + e1 + e2;
        wsm[0] = e0 / s; wsm[1] = e1 / s; wsm[2] = e2 / s;
    }
}

// ---------------- fused pass 1: double-bucket, LDS-sort, coalesced write -----
// No edge staging: row/col re-read from global (L1-hot on 2nd pass).
__global__ void __launch_bounds__(P1_T) fused_p1(const int* __restrict__ row,
                                                 const int* __restrict__ col,
                                                 int* __restrict__ bcnt,
                                                 int* __restrict__ bcnt2,
                                                 u32* __restrict__ buck,
                                                 u16* __restrict__ buck2) {
    __shared__ u32 st1[EPB];
    __shared__ u16 st2[EPB];
    __shared__ u8  sb1[EPB];
    __shared__ u8  sb2[EPB];
    __shared__ int h[BKT], h2[BKT];        // counts -> inclusive scan -> cursors
    __shared__ int hoff[BKT], hoff2[BKT];  // local exclusive offsets
    __shared__ int resv[BKT], resv2[BKT];  // global base reservations
    int t = threadIdx.x;
    int beg = blockIdx.x * EPB, end = min(NE, beg + EPB);
    int n = end - beg;
    for (int i = t; i < BKT; i += P1_T) { h[i] = 0; h2[i] = 0; }
    __syncthreads();
    // pass A: bucket histograms
    for (int i = t; i < n; i += P1_T) {
        atomicAdd(&h[row[beg + i] / BROWS], 1);
        atomicAdd(&h2[col[beg + i] / BROWS], 1);
    }
    __syncthreads();
    // dual in-place Hillis-Steele inclusive scan (threads 0-255: h, 256-511: h2)
    int id = t & 255;
    int side = t >> 8;
    int* arr = (side == 0) ? h : h2;
    int myc = arr[id];
    for (int st = 1; st < BKT; st <<= 1) {
        int u = (id >= st) ? arr[id - st] : 0;
        __syncthreads();
        arr[id] += u;
        __syncthreads();
    }
    if (side == 0) {
        hoff[id] = h[id] - myc;
        resv[id] = atomicAdd(&bcnt[id], myc);
    } else {
        hoff2[id] = h2[id] - myc;
        resv2[id] = atomicAdd(&bcnt2[id], myc);
    }
    __syncthreads();
    if (t < BKT) h[t] = hoff[t];
    else h2[t - BKT] = hoff2[t - BKT];
    __syncthreads();
    // pass B: scatter into LDS staged arrays (bucket-sorted)
    for (int i = t; i < n; i += P1_T) {
        int r = row[beg + i], c = col[beg + i];
        int b1 = r / BROWS;
        int pos = atomicAdd(&h[b1], 1);
        st1[pos] = ((u32)(r - b1 * BROWS) << 17) | (u32)c;
        sb1[pos] = (u8)b1;
        int b2 = c / BROWS;
        int pos2 = atomicAdd(&h2[b2], 1);
        st2[pos2] = (u16)(c - b2 * BROWS);
        sb2[pos2] = (u8)b2;
    }
    __syncthreads();
    // coalesced write-out (consecutive i -> consecutive dest within bucket runs)
    for (int i = t; i < n; i += P1_T) {
        int b1 = sb1[i];
        buck[(size_t)b1 * CAP + resv[b1] + (i - hoff[b1])] = st1[i];
        int b2 = sb2[i];
        buck2[(size_t)b2 * CAP + resv2[b2] + (i - hoff2[b2])] = st2[i];
    }
}

// ---------------- merged build: blocks 0-255 degree+scale, 256-511 CSR build ---
__global__ void __launch_bounds__(1024) build_both(const int* __restrict__ bcnt,
                                                   const u32* __restrict__ buck,
                                                   int* __restrict__ adjc,
                                                   int2* __restrict__ rowbe,
                                                   const int* __restrict__ bcnt2,
                                                   const u16* __restrict__ buck2,
                                                   float* __restrict__ dis,
                                                   float* __restrict__ dsi,
                                                   const float4* __restrict__ x,
                                                   ushort4* __restrict__ y1,
                                                   ushort4* __restrict__ y2) {
    __shared__ int ca[BROWS];
    __shared__ int wsum[16];
    int t = threadIdx.x;
    if (blockIdx.x < BKT) {
        // ---- degree + scale (col side) ----
        int b = blockIdx.x;
        int row0 = b * BROWS;
        int nrows = min(BROWS, NN - row0);
        int cntb = bcnt2[b];
        const u16* eb = buck2 + (size_t)b * CAP;
        for (int i = t; i < nrows; i += 1024) ca[i] = 0;
        __syncthreads();
        for (int e = t; e < cntb; e += 1024)
            atomicAdd(&ca[eb[e]], 1);
        __syncthreads();
        if (t < nrows) {
            float dg = (float)(ca[t] + 1);     // +1 self loop, always > 0
            dis[row0 + t] = rsqrtf(dg);
            dsi[row0 + t] = sqrtf(dg);
        }
        int items = nrows * 16;                 // float4 quads in this row range
        for (int i = t; i < items; i += 1024) {
            int r = i >> 4;
            float s = rsqrtf((float)(ca[r] + 1));
            int gidx = (row0 + r) * 16 + (i & 15);
            float4 v = x[gidx];
            ushort4 o;
            o.x = f2bf(s * v.x); o.y = f2bf(s * v.y); o.z = f2bf(s * v.z); o.w = f2bf(s * v.w);
            y1[gidx] = o;
        }
        if (b == BKT - 1 && t < 16) {           // sentinel row NN
            ushort4 z = {0, 0, 0, 0};
            y1[NN * 16 + t] = z;
            y2[NN * 16 + t] = z;
        }
    } else {
        // ---- CSR build (row side) ----
        int b = blockIdx.x - BKT;
        int row0 = b * BROWS;
        int nrows = min(BROWS, NN - row0);
        int cntb = bcnt[b];
        const u32* eb = buck + (size_t)b * CAP;
        for (int i = t; i < nrows; i += 1024) ca[i] = 0;
        __syncthreads();
        for (int e = t; e < cntb; e += 1024)
            atomicAdd(&ca[eb[e] >> 17], 1);
        __syncthreads();
        int v = (t < nrows) ? ca[t] : 0;
        int vp = (v + 15) & ~15;             // pad row length to multiple of 16
        int lane = t & 63, wv = t >> 6;
        int incl = vp;
        #pragma unroll
        for (int d = 1; d < 64; d <<= 1) {
            int u = __shfl_up(incl, d);
            if (lane >= d) incl += u;
        }
        if (lane == 63) wsum[wv] = incl;
        __syncthreads();
        if (t < 16) {
            int s = wsum[t];
            #pragma unroll
            for (int d = 1; d < 16; d <<= 1) {
                int u = __shfl_up(s, d, 16);
                if (t >= d) s += u;
            }
            wsum[t] = s;
        }
        __syncthreads();
        int excl = ((wv > 0) ? wsum[wv - 1] : 0) + incl - vp;
        if (t < nrows) {
            int base = b * PADCAP + excl;
            rowbe[row0 + t] = make_int2(base, base + vp);
            for (int p = base + v; p < base + vp; ++p) adjc[p] = NN;  // sentinel pads
            ca[t] = base;                    // cursor = global position
        }
        __syncthreads();
        for (int e = t; e < cntb; e += 1024) {
            u32 p = eb[e];
            int pos = atomicAdd(&ca[p >> 17], 1);
            adjc[pos] = (int)(p & 0x1FFFFu);
        }
    }
}

// ---------------- propagate kernels (gather, no atomics) ----------------
// TWO nodes per wave (lanes 0-31 / 32-63). Per half: sg=(l>>3)&3, ho=l&7.
// Rows padded to x16 -> uniform loop of {int4 adjc + 4 us8 gathers}, no tails.
// Sentinel edges hit the zeroed row NN (one hot line, L1-resident).

__global__ void prop1_kernel(const int2* __restrict__ rowbe,
                             const int* __restrict__ adjc,
                             const float* __restrict__ dis,
                             const u16* __restrict__ y1,
                             u16* __restrict__ y2) {
    int tid = blockIdx.x * blockDim.x + threadIdx.x;
    int w = tid >> 6, l = tid & 63;
    int n = 2 * w + (l >> 5);
    int sg = (l >> 3) & 3;
    int ho = l & 7;
    int2 be = rowbe[n];
    float a[8] = {0.f, 0.f, 0.f, 0.f, 0.f, 0.f, 0.f, 0.f};
    #pragma unroll 2
    for (int j = be.x; j < be.y; j += 16) {
        int4 c = *(const int4*)&adjc[j + sg * 4];
        us8 v0 = *(const us8*)&y1[c.x * D + ho * 8];
        us8 v1 = *(const us8*)&y1[c.y * D + ho * 8];
        us8 v2 = *(const us8*)&y1[c.z * D + ho * 8];
        us8 v3 = *(const us8*)&y1[c.w * D + ho * 8];
        #pragma unroll
        for (int k = 0; k < 8; ++k)
            a[k] += (bf2f(v0[k]) + bf2f(v1[k])) + (bf2f(v2[k]) + bf2f(v3[k]));
    }
    #pragma unroll
    for (int k = 0; k < 8; ++k) {
        a[k] += __shfl_xor(a[k], 8);
        a[k] += __shfl_xor(a[k], 16);
    }
    if ((l & 31) < 8) {
        us8 s = *(const us8*)&y1[n * D + ho * 8];   // self loop
        float di = dis[n], d2 = di * di;
        us8 o;
        #pragma unroll
        for (int k = 0; k < 8; ++k) o[k] = f2bf(d2 * (a[k] + bf2f(s[k])));
        *(us8*)&y2[n * D + ho * 8] = o;
    }
}

// out = dsi*(w0*y1[n] + w1*y2[n]) + w2*di*(y2[n] + sum_c y2[c])
__global__ void prop2_kernel(const int2* __restrict__ rowbe,
                             const int* __restrict__ adjc,
                             const float* __restrict__ dis,
                             const float* __restrict__ dsi,
                             const u16* __restrict__ y1,
                             const u16* __restrict__ y2,
                             const float* __restrict__ wsm,
                             float* __restrict__ out) {
    int tid = blockIdx.x * blockDim.x + threadIdx.x;
    int w = tid >> 6, l = tid & 63;
    int n = 2 * w + (l >> 5);
    int sg = (l >> 3) & 3;
    int ho = l & 7;
    int2 be = rowbe[n];
    float a[8] = {0.f, 0.f, 0.f, 0.f, 0.f, 0.f, 0.f, 0.f};
    #pragma unroll 2
    for (int j = be.x; j < be.y; j += 16) {
        int4 c = *(const int4*)&adjc[j + sg * 4];
        us8 v0 = *(const us8*)&y2[c.x * D + ho * 8];
        us8 v1 = *(const us8*)&y2[c.y * D + ho * 8];
        us8 v2 = *(const us8*)&y2[c.z * D + ho * 8];
        us8 v3 = *(const us8*)&y2[c.w * D + ho * 8];
        #pragma unroll
        for (int k = 0; k < 8; ++k)
            a[k] += (bf2f(v0[k]) + bf2f(v1[k])) + (bf2f(v2[k]) + bf2f(v3[k]));
    }
    #pragma unroll
    for (int k = 0; k < 8; ++k) {
        a[k] += __shfl_xor(a[k], 8);
        a[k] += __shfl_xor(a[k], 16);
    }
    if ((l & 31) < 8) {
        us8 s1 = *(const us8*)&y1[n * D + ho * 8];
        us8 s2 = *(const us8*)&y2[n * D + ho * 8];
        float di = dis[n], ds = dsi[n];
        float w0 = wsm[0], w1 = wsm[1], w2 = wsm[2];
        float o[8];
        #pragma unroll
        for (int k = 0; k < 8; ++k) {
            float y2k = bf2f(s2[k]);
            o[k] = ds * (w0 * bf2f(s1[k]) + w1 * y2k) + w2 * (di * (a[k] + y2k));
        }
        float4 o0 = {o[0], o[1], o[2], o[3]};
        float4 o1 = {o[4], o[5], o[6], o[7]};
        *(float4*)&out[n * D + ho * 8] = o0;
        *(float4*)&out[n * D + ho * 8 + 4] = o1;
    }
}

// ---------------- launch ----------------

extern "C" void kernel_launch(void* const* d_in, const int* in_sizes, int n_in,
                              void* d_out, int out_size, void* d_ws, size_t ws_size,
                              hipStream_t stream) {
    const float* x   = (const float*)d_in[0];
    const int*   ei  = (const int*)d_in[1];   // [2, NE]
    const float* hw  = (const float*)d_in[2]; // [3]
    float*       out = (float*)d_out;

    const int* row = ei;       // scatter destination
    const int* col = ei + NE;  // gather source

    char* ws = (char*)d_ws;
    size_t off = 0;
    auto alloc = [&](size_t bytes) { size_t p = off; off += (bytes + 255) & ~(size_t)255; return p; };
    float* wsm    = (float*)(ws + alloc(16));
    int*   bcnt   = (int*)  (ws + alloc((size_t)BKT * 4));
    int*   bcnt2  = (int*)  (ws + alloc((size_t)BKT * 4));
    float* dis    = (float*)(ws + alloc((size_t)NN * 4));
    float* dsi    = (float*)(ws + alloc((size_t)NN * 4));
    u32*   buck   = (u32*)  (ws + alloc((size_t)BKT * CAP * 4));
    u16*   buck2  = (u16*)  (ws + alloc((size_t)BKT * CAP * 2));
    int*   adjc   = (int*)  (ws + alloc((size_t)BKT * PADCAP * 4));
    int2*  rowbe  = (int2*) (ws + alloc((size_t)NN * 8));
    u16*   y1     = (u16*)  (ws + alloc((size_t)(NN + 1) * D * 2));
    u16*   y2     = (u16*)  (ws + alloc((size_t)(NN + 1) * D * 2));

    setup_kernel<<<1, 1024, 0, stream>>>(hw, wsm, bcnt, bcnt2);
    fused_p1<<<P1_NB, P1_T, 0, stream>>>(row, col, bcnt, bcnt2, buck, buck2);
    build_both<<<2 * BKT, 1024, 0, stream>>>(bcnt, buck, adjc, rowbe,
                                             bcnt2, buck2, dis, dsi,
                                             (const float4*)x, (ushort4*)y1, (ushort4*)y2);

    // 2 nodes per wave: NN/2 waves; 4 waves per 256-thread block.
    const int prop_blocks = (NN / 2 + 3) / 4; // 12500
    prop1_kernel<<<prop_blocks, 256, 0, stream>>>(rowbe, adjc, dis, y1, y2);
    prop2_kernel<<<prop_blocks, 256, 0, stream>>>(rowbe, adjc, dis, dsi, y1, y2, wsm, out);
}

// Round 15
// 111.946 us; speedup vs baseline: 1.1126x; 1.1126x over previous
//
#include <hip/hip_runtime.h>

#define NN 100000
#define NE 1600000
#define D 64

#define BKT 256                          // buckets (both row- and col-space)
#define BROWS ((NN + BKT - 1) / BKT)     // 391 per bucket (fits 9 bits)
#define CAP 8192                         // buck slots per bucket (mean 6250, sigma 79)
#define PADCAP 12288                     // adjc slots per bucket (rows padded to x16)
#define P1_NB 512                        // pass-1 blocks
#define P1_T 1024                        // pass-1 threads per block
#define EPB ((NE + P1_NB - 1) / P1_NB)   // 3125 edges per pass-1 block

typedef unsigned short u16;
typedef unsigned int u32;
typedef unsigned char u8;
typedef __attribute__((ext_vector_type(8))) unsigned short us8;

// ---------------- bf16 helpers (bit-level, RNE) ----------------

__device__ __forceinline__ float bf2f(u16 u) {
    union { u32 i; float f; } x; x.i = ((u32)u) << 16; return x.f;
}
__device__ __forceinline__ u16 f2bf(float f) {
    union { float f; u32 i; } x; x.f = f;
    u32 r = x.i + 0x7FFF + ((x.i >> 16) & 1);   // round-to-nearest-even
    return (u16)(r >> 16);
}

// Setup: zero bucket counters + softmax of the 3 hop weights.
__global__ void setup_kernel(const float* __restrict__ hw, float* __restrict__ wsm,
                             int* __restrict__ bcnt, int* __restrict__ bcnt2) {
    int t = threadIdx.x;
    if (t < BKT) bcnt[t] = 0;
    else if (t < 2 * BKT) bcnt2[t - BKT] = 0;
    else if (t == 2 * BKT) {
        float m = fmaxf(fmaxf(hw[0], hw[1]), hw[2]);
        float e0 = expf(hw[0] - m), e1 = expf(hw[1] - m), e2 = expf(hw[2] - m);
        float s = e0 + e1 + e2;
        wsm[0] = e0 / s; wsm[1] = e1 / s; wsm[2] = e2 / s;
    }
}

// ---------------- fused pass 1 (R13 staged version): stage edges in LDS,
// double-bucket, LDS-sort, coalesced write-out ----
__global__ void __launch_bounds__(P1_T) fused_p1(const int* __restrict__ row,
                                                 const int* __restrict__ col,
                                                 int* __restrict__ bcnt,
                                                 int* __restrict__ bcnt2,
                                                 u32* __restrict__ buck,
                                                 u16* __restrict__ buck2) {
    __shared__ int lds_r[EPB];
    __shared__ int lds_c[EPB];
    __shared__ u32 st1[EPB];
    __shared__ u16 st2[EPB];
    __shared__ u8  sb1[EPB];
    __shared__ u8  sb2[EPB];
    __shared__ int h[BKT], h2[BKT];        // counts -> inclusive scan -> cursors
    __shared__ int hoff[BKT], hoff2[BKT];  // local exclusive offsets
    __shared__ int resv[BKT], resv2[BKT];  // global base reservations
    int t = threadIdx.x;
    int beg = blockIdx.x * EPB, end = min(NE, beg + EPB);
    int n = end - beg;
    for (int i = t; i < BKT; i += P1_T) { h[i] = 0; h2[i] = 0; }
    __syncthreads();
    // stage + both bucket histograms
    for (int i = t; i < n; i += P1_T) {
        int r = row[beg + i], c = col[beg + i];
        lds_r[i] = r; lds_c[i] = c;
        atomicAdd(&h[r / BROWS], 1);
        atomicAdd(&h2[c / BROWS], 1);
    }
    __syncthreads();
    // dual in-place Hillis-Steele inclusive scan (threads 0-255: h, 256-511: h2)
    int id = t & 255;
    int side = t >> 8;
    int* arr = (side == 0) ? h : h2;
    int myc = (side < 2) ? arr[id] : 0;
    for (int st = 1; st < BKT; st <<= 1) {
        int u = 0;
        if (side < 2 && id >= st) u = arr[id - st];
        __syncthreads();
        if (side < 2) arr[id] += u;
        __syncthreads();
    }
    if (side == 0) {
        hoff[id] = h[id] - myc;
        resv[id] = atomicAdd(&bcnt[id], myc);
    } else if (side == 1) {
        hoff2[id] = h2[id] - myc;
        resv2[id] = atomicAdd(&bcnt2[id], myc);
    }
    __syncthreads();
    if (t < BKT) h[t] = hoff[t];
    else if (t < 2 * BKT) h2[t - BKT] = hoff2[t - BKT];
    __syncthreads();
    // scatter into LDS staged arrays (bucket-sorted)
    for (int i = t; i < n; i += P1_T) {
        int r = lds_r[i], c = lds_c[i];
        int b1 = r / BROWS;
        int pos = atomicAdd(&h[b1], 1);
        st1[pos] = ((u32)(r - b1 * BROWS) << 17) | (u32)c;
        sb1[pos] = (u8)b1;
        int b2 = c / BROWS;
        int pos2 = atomicAdd(&h2[b2], 1);
        st2[pos2] = (u16)(c - b2 * BROWS);
        sb2[pos2] = (u8)b2;
    }
    __syncthreads();
    // coalesced write-out (consecutive i -> consecutive dest within bucket runs)
    for (int i = t; i < n; i += P1_T) {
        int b1 = sb1[i];
        buck[(size_t)b1 * CAP + resv[b1] + (i - hoff[b1])] = st1[i];
        int b2 = sb2[i];
        buck2[(size_t)b2 * CAP + resv2[b2] + (i - hoff2[b2])] = st2[i];
    }
}

// ---------------- merged build: blocks 0-255 degree+scale, 256-511 CSR build ---
__global__ void __launch_bounds__(1024) build_both(const int* __restrict__ bcnt,
                                                   const u32* __restrict__ buck,
                                                   int* __restrict__ adjc,
                                                   int2* __restrict__ rowbe,
                                                   const int* __restrict__ bcnt2,
                                                   const u16* __restrict__ buck2,
                                                   float* __restrict__ dis,
                                                   float* __restrict__ dsi,
                                                   const float4* __restrict__ x,
                                                   ushort4* __restrict__ y1,
                                                   ushort4* __restrict__ y2) {
    __shared__ int ca[BROWS];
    __shared__ int wsum[16];
    int t = threadIdx.x;
    if (blockIdx.x < BKT) {
        // ---- degree + scale (col side) ----
        int b = blockIdx.x;
        int row0 = b * BROWS;
        int nrows = min(BROWS, NN - row0);
        int cntb = bcnt2[b];
        const u16* eb = buck2 + (size_t)b * CAP;
        for (int i = t; i < nrows; i += 1024) ca[i] = 0;
        __syncthreads();
        for (int e = t; e < cntb; e += 1024)
            atomicAdd(&ca[eb[e]], 1);
        __syncthreads();
        if (t < nrows) {
            float dg = (float)(ca[t] + 1);     // +1 self loop, always > 0
            dis[row0 + t] = rsqrtf(dg);
            dsi[row0 + t] = sqrtf(dg);
        }
        int items = nrows * 16;                 // float4 quads in this row range
        for (int i = t; i < items; i += 1024) {
            int r = i >> 4;
            float s = rsqrtf((float)(ca[r] + 1));
            int gidx = (row0 + r) * 16 + (i & 15);
            float4 v = x[gidx];
            ushort4 o;
            o.x = f2bf(s * v.x); o.y = f2bf(s * v.y); o.z = f2bf(s * v.z); o.w = f2bf(s * v.w);
            y1[gidx] = o;
        }
        if (b == BKT - 1 && t < 16) {           // sentinel row NN
            ushort4 z = {0, 0, 0, 0};
            y1[NN * 16 + t] = z;
            y2[NN * 16 + t] = z;
        }
    } else {
        // ---- CSR build (row side) ----
        int b = blockIdx.x - BKT;
        int row0 = b * BROWS;
        int nrows = min(BROWS, NN - row0);
        int cntb = bcnt[b];
        const u32* eb = buck + (size_t)b * CAP;
        for (int i = t; i < nrows; i += 1024) ca[i] = 0;
        __syncthreads();
        for (int e = t; e < cntb; e += 1024)
            atomicAdd(&ca[eb[e] >> 17], 1);
        __syncthreads();
        int v = (t < nrows) ? ca[t] : 0;
        int vp = (v + 15) & ~15;             // pad row length to multiple of 16
        int lane = t & 63, wv = t >> 6;
        int incl = vp;
        #pragma unroll
        for (int d = 1; d < 64; d <<= 1) {
            int u = __shfl_up(incl, d);
            if (lane >= d) incl += u;
        }
        if (lane == 63) wsum[wv] = incl;
        __syncthreads();
        if (t < 16) {
            int s = wsum[t];
            #pragma unroll
            for (int d = 1; d < 16; d <<= 1) {
                int u = __shfl_up(s, d, 16);
                if (t >= d) s += u;
            }
            wsum[t] = s;
        }
        __syncthreads();
        int excl = ((wv > 0) ? wsum[wv - 1] : 0) + incl - vp;
        if (t < nrows) {
            int base = b * PADCAP + excl;
            rowbe[row0 + t] = make_int2(base, base + vp);
            for (int p = base + v; p < base + vp; ++p) adjc[p] = NN;  // sentinel pads
            ca[t] = base;                    // cursor = global position
        }
        __syncthreads();
        for (int e = t; e < cntb; e += 1024) {
            u32 p = eb[e];
            int pos = atomicAdd(&ca[p >> 17], 1);
            adjc[pos] = (int)(p & 0x1FFFFu);
        }
    }
}

// ---------------- propagate kernels (gather, no atomics) ----------------
// TWO nodes per wave (lanes 0-31 / 32-63). Per half: sg=(l>>3)&3, ho=l&7.
// Rows padded to x16 -> uniform loop of {int4 adjc + 4 us8 gathers}, no tails.
// Sentinel edges hit the zeroed row NN (one hot line, L1-resident).

__global__ void prop1_kernel(const int2* __restrict__ rowbe,
                             const int* __restrict__ adjc,
                             const float* __restrict__ dis,
                             const u16* __restrict__ y1,
                             u16* __restrict__ y2) {
    int tid = blockIdx.x * blockDim.x + threadIdx.x;
    int w = tid >> 6, l = tid & 63;
    int n = 2 * w + (l >> 5);
    int sg = (l >> 3) & 3;
    int ho = l & 7;
    int2 be = rowbe[n];
    float a[8] = {0.f, 0.f, 0.f, 0.f, 0.f, 0.f, 0.f, 0.f};
    #pragma unroll 2
    for (int j = be.x; j < be.y; j += 16) {
        int4 c = *(const int4*)&adjc[j + sg * 4];
        us8 v0 = *(const us8*)&y1[c.x * D + ho * 8];
        us8 v1 = *(const us8*)&y1[c.y * D + ho * 8];
        us8 v2 = *(const us8*)&y1[c.z * D + ho * 8];
        us8 v3 = *(const us8*)&y1[c.w * D + ho * 8];
        #pragma unroll
        for (int k = 0; k < 8; ++k)
            a[k] += (bf2f(v0[k]) + bf2f(v1[k])) + (bf2f(v2[k]) + bf2f(v3[k]));
    }
    #pragma unroll
    for (int k = 0; k < 8; ++k) {
        a[k] += __shfl_xor(a[k], 8);
        a[k] += __shfl_xor(a[k], 16);
    }
    if ((l & 31) < 8) {
        us8 s = *(const us8*)&y1[n * D + ho * 8];   // self loop
        float di = dis[n], d2 = di * di;
        us8 o;
        #pragma unroll
        for (int k = 0; k < 8; ++k) o[k] = f2bf(d2 * (a[k] + bf2f(s[k])));
        *(us8*)&y2[n * D + ho * 8] = o;
    }
}

// out = dsi*(w0*y1[n] + w1*y2[n]) + w2*di*(y2[n] + sum_c y2[c])
__global__ void prop2_kernel(const int2* __restrict__ rowbe,
                             const int* __restrict__ adjc,
                             const float* __restrict__ dis,
                             const float* __restrict__ dsi,
                             const u16* __restrict__ y1,
                             const u16* __restrict__ y2,
                             const float* __restrict__ wsm,
                             float* __restrict__ out) {
    int tid = blockIdx.x * blockDim.x + threadIdx.x;
    int w = tid >> 6, l = tid & 63;
    int n = 2 * w + (l >> 5);
    int sg = (l >> 3) & 3;
    int ho = l & 7;
    int2 be = rowbe[n];
    float a[8] = {0.f, 0.f, 0.f, 0.f, 0.f, 0.f, 0.f, 0.f};
    #pragma unroll 2
    for (int j = be.x; j < be.y; j += 16) {
        int4 c = *(const int4*)&adjc[j + sg * 4];
        us8 v0 = *(const us8*)&y2[c.x * D + ho * 8];
        us8 v1 = *(const us8*)&y2[c.y * D + ho * 8];
        us8 v2 = *(const us8*)&y2[c.z * D + ho * 8];
        us8 v3 = *(const us8*)&y2[c.w * D + ho * 8];
        #pragma unroll
        for (int k = 0; k < 8; ++k)
            a[k] += (bf2f(v0[k]) + bf2f(v1[k])) + (bf2f(v2[k]) + bf2f(v3[k]));
    }
    #pragma unroll
    for (int k = 0; k < 8; ++k) {
        a[k] += __shfl_xor(a[k], 8);
        a[k] += __shfl_xor(a[k], 16);
    }
    if ((l & 31) < 8) {
        us8 s1 = *(const us8*)&y1[n * D + ho * 8];
        us8 s2 = *(const us8*)&y2[n * D + ho * 8];
        float di = dis[n], ds = dsi[n];
        float w0 = wsm[0], w1 = wsm[1], w2 = wsm[2];
        float o[8];
        #pragma unroll
        for (int k = 0; k < 8; ++k) {
            float y2k = bf2f(s2[k]);
            o[k] = ds * (w0 * bf2f(s1[k]) + w1 * y2k) + w2 * (di * (a[k] + y2k));
        }
        float4 o0 = {o[0], o[1], o[2], o[3]};
        float4 o1 = {o[4], o[5], o[6], o[7]};
        *(float4*)&out[n * D + ho * 8] = o0;
        *(float4*)&out[n * D + ho * 8 + 4] = o1;
    }
}

// ---------------- launch ----------------

extern "C" void kernel_launch(void* const* d_in, const int* in_sizes, int n_in,
                              void* d_out, int out_size, void* d_ws, size_t ws_size,
                              hipStream_t stream) {
    const float* x   = (const float*)d_in[0];
    const int*   ei  = (const int*)d_in[1];   // [2, NE]
    const float* hw  = (const float*)d_in[2]; // [3]
    float*       out = (float*)d_out;

    const int* row = ei;       // scatter destination
    const int* col = ei + NE;  // gather source

    char* ws = (char*)d_ws;
    size_t off = 0;
    auto alloc = [&](size_t bytes) { size_t p = off; off += (bytes + 255) & ~(size_t)255; return p; };
    float* wsm    = (float*)(ws + alloc(16));
    int*   bcnt   = (int*)  (ws + alloc((size_t)BKT * 4));
    int*   bcnt2  = (int*)  (ws + alloc((size_t)BKT * 4));
    float* dis    = (float*)(ws + alloc((size_t)NN * 4));
    float* dsi    = (float*)(ws + alloc((size_t)NN * 4));
    u32*   buck   = (u32*)  (ws + alloc((size_t)BKT * CAP * 4));
    u16*   buck2  = (u16*)  (ws + alloc((size_t)BKT * CAP * 2));
    int*   adjc   = (int*)  (ws + alloc((size_t)BKT * PADCAP * 4));
    int2*  rowbe  = (int2*) (ws + alloc((size_t)NN * 8));
    u16*   y1     = (u16*)  (ws + alloc((size_t)(NN + 1) * D * 2));
    u16*   y2     = (u16*)  (ws + alloc((size_t)(NN + 1) * D * 2));

    setup_kernel<<<1, 1024, 0, stream>>>(hw, wsm, bcnt, bcnt2);
    fused_p1<<<P1_NB, P1_T, 0, stream>>>(row, col, bcnt, bcnt2, buck, buck2);
    build_both<<<2 * BKT, 1024, 0, stream>>>(bcnt, buck, adjc, rowbe,
                                             bcnt2, buck2, dis, dsi,
                                             (const float4*)x, (ushort4*)y1, (ushort4*)y2);

    // 2 nodes per wave: NN/2 waves; 4 waves per 256-thread block.
    const int prop_blocks = (NN / 2 + 3) / 4; // 12500
    prop1_kernel<<<prop_blocks, 256, 0, stream>>>(rowbe, adjc, dis, y1, y2);
    prop2_kernel<<<prop_blocks, 256, 0, stream>>>(rowbe, adjc, dis, dsi, y1, y2, wsm, out);
}

// Round 16
// 110.906 us; speedup vs baseline: 1.1230x; 1.0094x over previous
//
#include <hip/hip_runtime.h>

#define NN 100000
#define NE 1600000
#define D 64

#define BKT 256                          // buckets (both row- and col-space)
#define BROWS ((NN + BKT - 1) / BKT)     // 391 per bucket (fits 9 bits)
#define CAP 8192                         // buck slots per bucket (mean 6250, sigma 79)
#define PADCAP 12288                     // adjc slots per bucket (rows padded to x16)
#define P1_NB 512                        // pass-1 blocks
#define P1_T 1024                        // pass-1 threads per block
#define EPB ((NE + P1_NB - 1) / P1_NB)   // 3125 edges per pass-1 block

typedef unsigned short u16;
typedef unsigned int u32;
typedef unsigned char u8;
typedef __attribute__((ext_vector_type(8))) unsigned short us8;

// ---------------- bf16 helpers (bit-level, RNE) ----------------

__device__ __forceinline__ float bf2f(u16 u) {
    union { u32 i; float f; } x; x.i = ((u32)u) << 16; return x.f;
}
__device__ __forceinline__ u16 f2bf(float f) {
    union { float f; u32 i; } x; x.f = f;
    u32 r = x.i + 0x7FFF + ((x.i >> 16) & 1);   // round-to-nearest-even
    return (u16)(r >> 16);
}

// Setup: zero bucket counters + softmax of the 3 hop weights.
__global__ void setup_kernel(const float* __restrict__ hw, float* __restrict__ wsm,
                             int* __restrict__ bcnt, int* __restrict__ bcnt2) {
    int t = threadIdx.x;
    if (t < BKT) bcnt[t] = 0;
    else if (t < 2 * BKT) bcnt2[t - BKT] = 0;
    else if (t == 2 * BKT) {
        float m = fmaxf(fmaxf(hw[0], hw[1]), hw[2]);
        float e0 = expf(hw[0] - m), e1 = expf(hw[1] - m), e2 = expf(hw[2] - m);
        float s = e0 + e1 + e2;
        wsm[0] = e0 / s; wsm[1] = e1 / s; wsm[2] = e2 / s;
    }
}

// ---------------- fused pass 1: register-staged edges, double-bucket,
// shfl-scan, LDS-sort, coalesced write-out ----
__global__ void __launch_bounds__(P1_T) fused_p1(const int* __restrict__ row,
                                                 const int* __restrict__ col,
                                                 int* __restrict__ bcnt,
                                                 int* __restrict__ bcnt2,
                                                 u32* __restrict__ buck,
                                                 u16* __restrict__ buck2) {
    __shared__ u32 st1[EPB];
    __shared__ u16 st2[EPB];
    __shared__ u8  sb1[EPB];
    __shared__ u8  sb2[EPB];
    __shared__ int h[BKT], h2[BKT];        // counts -> cursors
    __shared__ int hoff[BKT], hoff2[BKT];  // local exclusive offsets
    __shared__ int resv[BKT], resv2[BKT];  // global base reservations
    __shared__ int wscan[8];               // per-wave partial sums (2 sides x 4 waves)
    int t = threadIdx.x;
    int beg = blockIdx.x * EPB, end = min(NE, beg + EPB);
    int n = end - beg;
    if (t < BKT) h[t] = 0;
    else if (t < 2 * BKT) h2[t - BKT] = 0;
    __syncthreads();
    // phase A: load edges into REGISTERS (<=4/thread) + bucket histograms
    int rr[4], cc[4];
    #pragma unroll
    for (int k = 0; k < 4; ++k) {
        int i = t + k * P1_T;
        if (i < n) {
            rr[k] = row[beg + i];
            cc[k] = col[beg + i];
            atomicAdd(&h[rr[k] / BROWS], 1);
            atomicAdd(&h2[cc[k] / BROWS], 1);
        } else {
            rr[k] = -1; cc[k] = 0;
        }
    }
    __syncthreads();
    // dual 256-scan: wave shfl-scan + 8-entry combine (2 barriers total)
    int id = t & 255, side = t >> 8, lane = t & 63, wv = (t >> 6) & 3;
    int v = 0, incl = 0;
    if (t < 2 * BKT) {
        v = side ? h2[id] : h[id];
        incl = v;
        #pragma unroll
        for (int d = 1; d < 64; d <<= 1) {
            int u = __shfl_up(incl, d);
            if (lane >= d) incl += u;
        }
        if (lane == 63) wscan[t >> 6] = incl;
    }
    __syncthreads();
    if (t < 2 * BKT) {
        int base = 0;
        #pragma unroll
        for (int k = 0; k < 3; ++k)
            if (wv > k) base += wscan[(side << 2) | k];
        int excl = base + incl - v;
        if (side == 0) {
            hoff[id] = excl;
            resv[id] = atomicAdd(&bcnt[id], v);
            h[id] = excl;                  // cursor
        } else {
            hoff2[id] = excl;
            resv2[id] = atomicAdd(&bcnt2[id], v);
            h2[id] = excl;                 // cursor
        }
    }
    __syncthreads();
    // phase B: scatter from registers into LDS staged arrays (bucket-sorted)
    #pragma unroll
    for (int k = 0; k < 4; ++k) {
        if (rr[k] >= 0) {
            int r = rr[k], c = cc[k];
            int b1 = r / BROWS;
            int pos = atomicAdd(&h[b1], 1);
            st1[pos] = ((u32)(r - b1 * BROWS) << 17) | (u32)c;
            sb1[pos] = (u8)b1;
            int b2 = c / BROWS;
            int pos2 = atomicAdd(&h2[b2], 1);
            st2[pos2] = (u16)(c - b2 * BROWS);
            sb2[pos2] = (u8)b2;
        }
    }
    __syncthreads();
    // coalesced write-out (consecutive i -> consecutive dest within bucket runs)
    for (int i = t; i < n; i += P1_T) {
        int b1 = sb1[i];
        buck[(size_t)b1 * CAP + resv[b1] + (i - hoff[b1])] = st1[i];
        int b2 = sb2[i];
        buck2[(size_t)b2 * CAP + resv2[b2] + (i - hoff2[b2])] = st2[i];
    }
}

// ---------------- merged build: blocks 0-255 degree+scale, 256-511 CSR build ---
__global__ void __launch_bounds__(1024) build_both(const int* __restrict__ bcnt,
                                                   const u32* __restrict__ buck,
                                                   int* __restrict__ adjc,
                                                   int2* __restrict__ rowbe,
                                                   const int* __restrict__ bcnt2,
                                                   const u16* __restrict__ buck2,
                                                   float* __restrict__ dis,
                                                   float* __restrict__ dsi,
                                                   const float4* __restrict__ x,
                                                   ushort4* __restrict__ y1,
                                                   ushort4* __restrict__ y2) {
    __shared__ int ca[BROWS];
    __shared__ int wsum[16];
    int t = threadIdx.x;
    if (blockIdx.x < BKT) {
        // ---- degree + scale (col side) ----
        int b = blockIdx.x;
        int row0 = b * BROWS;
        int nrows = min(BROWS, NN - row0);
        int cntb = bcnt2[b];
        const u16* eb = buck2 + (size_t)b * CAP;
        for (int i = t; i < nrows; i += 1024) ca[i] = 0;
        __syncthreads();
        for (int e = t; e < cntb; e += 1024)
            atomicAdd(&ca[eb[e]], 1);
        __syncthreads();
        if (t < nrows) {
            float dg = (float)(ca[t] + 1);     // +1 self loop, always > 0
            dis[row0 + t] = rsqrtf(dg);
            dsi[row0 + t] = sqrtf(dg);
        }
        int items = nrows * 16;                 // float4 quads in this row range
        for (int i = t; i < items; i += 1024) {
            int r = i >> 4;
            float s = rsqrtf((float)(ca[r] + 1));
            int gidx = (row0 + r) * 16 + (i & 15);
            float4 vv = x[gidx];
            ushort4 o;
            o.x = f2bf(s * vv.x); o.y = f2bf(s * vv.y); o.z = f2bf(s * vv.z); o.w = f2bf(s * vv.w);
            y1[gidx] = o;
        }
        if (b == BKT - 1 && t < 16) {           // sentinel row NN
            ushort4 z = {0, 0, 0, 0};
            y1[NN * 16 + t] = z;
            y2[NN * 16 + t] = z;
        }
    } else {
        // ---- CSR build (row side) ----
        int b = blockIdx.x - BKT;
        int row0 = b * BROWS;
        int nrows = min(BROWS, NN - row0);
        int cntb = bcnt[b];
        const u32* eb = buck + (size_t)b * CAP;
        for (int i = t; i < nrows; i += 1024) ca[i] = 0;
        __syncthreads();
        for (int e = t; e < cntb; e += 1024)
            atomicAdd(&ca[eb[e] >> 17], 1);
        __syncthreads();
        int v = (t < nrows) ? ca[t] : 0;
        int vp = (v + 15) & ~15;             // pad row length to multiple of 16
        int lane = t & 63, wv = t >> 6;
        int incl = vp;
        #pragma unroll
        for (int d = 1; d < 64; d <<= 1) {
            int u = __shfl_up(incl, d);
            if (lane >= d) incl += u;
        }
        if (lane == 63) wsum[wv] = incl;
        __syncthreads();
        if (t < 16) {
            int s = wsum[t];
            #pragma unroll
            for (int d = 1; d < 16; d <<= 1) {
                int u = __shfl_up(s, d, 16);
                if (t >= d) s += u;
            }
            wsum[t] = s;
        }
        __syncthreads();
        int excl = ((wv > 0) ? wsum[wv - 1] : 0) + incl - vp;
        if (t < nrows) {
            int base = b * PADCAP + excl;
            rowbe[row0 + t] = make_int2(base, base + vp);
            for (int p = base + v; p < base + vp; ++p) adjc[p] = NN;  // sentinel pads
            ca[t] = base;                    // cursor = global position
        }
        __syncthreads();
        for (int e = t; e < cntb; e += 1024) {
            u32 p = eb[e];
            int pos = atomicAdd(&ca[p >> 17], 1);
            adjc[pos] = (int)(p & 0x1FFFFu);
        }
    }
}

// ---------------- propagate kernels (gather, no atomics) ----------------
// TWO nodes per wave (lanes 0-31 / 32-63). Per half: sg=(l>>3)&3, ho=l&7.
// Rows padded to x16 -> uniform loop of {int4 adjc + 4 us8 gathers}, no tails.
// Self-loop/dis loads hoisted above the loop (extra line in flight).

__global__ void prop1_kernel(const int2* __restrict__ rowbe,
                             const int* __restrict__ adjc,
                             const float* __restrict__ dis,
                             const u16* __restrict__ y1,
                             u16* __restrict__ y2) {
    int tid = blockIdx.x * blockDim.x + threadIdx.x;
    int w = tid >> 6, l = tid & 63;
    int n = 2 * w + (l >> 5);
    int sg = (l >> 3) & 3;
    int ho = l & 7;
    int2 be = rowbe[n];
    us8 s = *(const us8*)&y1[n * D + ho * 8];   // self loop (independent, early)
    float di = dis[n];
    float a[8] = {0.f, 0.f, 0.f, 0.f, 0.f, 0.f, 0.f, 0.f};
    #pragma unroll 2
    for (int j = be.x; j < be.y; j += 16) {
        int4 c = *(const int4*)&adjc[j + sg * 4];
        us8 v0 = *(const us8*)&y1[c.x * D + ho * 8];
        us8 v1 = *(const us8*)&y1[c.y * D + ho * 8];
        us8 v2 = *(const us8*)&y1[c.z * D + ho * 8];
        us8 v3 = *(const us8*)&y1[c.w * D + ho * 8];
        #pragma unroll
        for (int k = 0; k < 8; ++k)
            a[k] += (bf2f(v0[k]) + bf2f(v1[k])) + (bf2f(v2[k]) + bf2f(v3[k]));
    }
    #pragma unroll
    for (int k = 0; k < 8; ++k) {
        a[k] += __shfl_xor(a[k], 8);
        a[k] += __shfl_xor(a[k], 16);
    }
    if ((l & 31) < 8) {
        float d2 = di * di;
        us8 o;
        #pragma unroll
        for (int k = 0; k < 8; ++k) o[k] = f2bf(d2 * (a[k] + bf2f(s[k])));
        *(us8*)&y2[n * D + ho * 8] = o;
    }
}

// out = dsi*(w0*y1[n] + w1*y2[n]) + w2*di*(y2[n] + sum_c y2[c])
__global__ void prop2_kernel(const int2* __restrict__ rowbe,
                             const int* __restrict__ adjc,
                             const float* __restrict__ dis,
                             const float* __restrict__ dsi,
                             const u16* __restrict__ y1,
                             const u16* __restrict__ y2,
                             const float* __restrict__ wsm,
                             float* __restrict__ out) {
    int tid = blockIdx.x * blockDim.x + threadIdx.x;
    int w = tid >> 6, l = tid & 63;
    int n = 2 * w + (l >> 5);
    int sg = (l >> 3) & 3;
    int ho = l & 7;
    int2 be = rowbe[n];
    us8 s1 = *(const us8*)&y1[n * D + ho * 8];  // independent, early
    us8 s2 = *(const us8*)&y2[n * D + ho * 8];
    float di = dis[n], ds = dsi[n];
    float a[8] = {0.f, 0.f, 0.f, 0.f, 0.f, 0.f, 0.f, 0.f};
    #pragma unroll 2
    for (int j = be.x; j < be.y; j += 16) {
        int4 c = *(const int4*)&adjc[j + sg * 4];
        us8 v0 = *(const us8*)&y2[c.x * D + ho * 8];
        us8 v1 = *(const us8*)&y2[c.y * D + ho * 8];
        us8 v2 = *(const us8*)&y2[c.z * D + ho * 8];
        us8 v3 = *(const us8*)&y2[c.w * D + ho * 8];
        #pragma unroll
        for (int k = 0; k < 8; ++k)
            a[k] += (bf2f(v0[k]) + bf2f(v1[k])) + (bf2f(v2[k]) + bf2f(v3[k]));
    }
    #pragma unroll
    for (int k = 0; k < 8; ++k) {
        a[k] += __shfl_xor(a[k], 8);
        a[k] += __shfl_xor(a[k], 16);
    }
    if ((l & 31) < 8) {
        float w0 = wsm[0], w1 = wsm[1], w2 = wsm[2];
        float o[8];
        #pragma unroll
        for (int k = 0; k < 8; ++k) {
            float y2k = bf2f(s2[k]);
            o[k] = ds * (w0 * bf2f(s1[k]) + w1 * y2k) + w2 * (di * (a[k] + y2k));
        }
        float4 o0 = {o[0], o[1], o[2], o[3]};
        float4 o1 = {o[4], o[5], o[6], o[7]};
        *(float4*)&out[n * D + ho * 8] = o0;
        *(float4*)&out[n * D + ho * 8 + 4] = o1;
    }
}

// ---------------- launch ----------------

extern "C" void kernel_launch(void* const* d_in, const int* in_sizes, int n_in,
                              void* d_out, int out_size, void* d_ws, size_t ws_size,
                              hipStream_t stream) {
    const float* x   = (const float*)d_in[0];
    const int*   ei  = (const int*)d_in[1];   // [2, NE]
    const float* hw  = (const float*)d_in[2]; // [3]
    float*       out = (float*)d_out;

    const int* row = ei;       // scatter destination
    const int* col = ei + NE;  // gather source

    char* ws = (char*)d_ws;
    size_t off = 0;
    auto alloc = [&](size_t bytes) { size_t p = off; off += (bytes + 255) & ~(size_t)255; return p; };
    float* wsm    = (float*)(ws + alloc(16));
    int*   bcnt   = (int*)  (ws + alloc((size_t)BKT * 4));
    int*   bcnt2  = (int*)  (ws + alloc((size_t)BKT * 4));
    float* dis    = (float*)(ws + alloc((size_t)NN * 4));
    float* dsi    = (float*)(ws + alloc((size_t)NN * 4));
    u32*   buck   = (u32*)  (ws + alloc((size_t)BKT * CAP * 4));
    u16*   buck2  = (u16*)  (ws + alloc((size_t)BKT * CAP * 2));
    int*   adjc   = (int*)  (ws + alloc((size_t)BKT * PADCAP * 4));
    int2*  rowbe  = (int2*) (ws + alloc((size_t)NN * 8));
    u16*   y1     = (u16*)  (ws + alloc((size_t)(NN + 1) * D * 2));
    u16*   y2     = (u16*)  (ws + alloc((size_t)(NN + 1) * D * 2));

    setup_kernel<<<1, 1024, 0, stream>>>(hw, wsm, bcnt, bcnt2);
    fused_p1<<<P1_NB, P1_T, 0, stream>>>(row, col, bcnt, bcnt2, buck, buck2);
    build_both<<<2 * BKT, 1024, 0, stream>>>(bcnt, buck, adjc, rowbe,
                                             bcnt2, buck2, dis, dsi,
                                             (const float4*)x, (ushort4*)y1, (ushort4*)y2);

    // 2 nodes per wave: NN/2 waves; 4 waves per 256-thread block.
    const int prop_blocks = (NN / 2 + 3) / 4; // 12500
    prop1_kernel<<<prop_blocks, 256, 0, stream>>>(rowbe, adjc, dis, y1, y2);
    prop2_kernel<<<prop_blocks, 256, 0, stream>>>(rowbe, adjc, dis, dsi, y1, y2, wsm, out);
}